// Round 11
// baseline (194.765 us; speedup 1.0000x reference)
//
#include <hip/hip_runtime.h>
#include <hip/hip_fp16.h>

#define NN 512          // N == M
#define DD 64           // feature dim
#define BIGF 1e10f
#define INV_LN2 1.44269504088896340736f
#define LN2 0.69314718055994530942f

// DP schedule (shared by both kernels):
// per batch: 256 threads = 4 waves; thread t owns rows 2t, 2t+1; l = t&63, w = t>>6.
// off(t) = l + 80*w; at step s, lane t processes column c = s - off(t).
// S[s][t] = half2( delta[2t][c], delta[2t+1][c] ) / ln2.
#define W0 80
#define TOTM 800        // 50 full 16-step blocks
#define EPI 15          // +15 epilogue steps -> last step s = 814
#define SROWS 832       // >= 814 + 16 prefetch + 1

// ======================= Phase 1: delta -> schedule-order S (proven r8) =======================
#define TS 128
#define XST 68          // LDS stage row stride (floats)
#define LST 66          // Ls row stride (dwords)

__global__ __launch_bounds__(256, 2)
void delta_kernel(const float* __restrict__ A, const float* __restrict__ Bm,
                  unsigned* __restrict__ S)   // S as uint (= half2) [b][SROWS][256]
{
  __shared__ __align__(16) float smem[2 * TS * XST];   // Xs|Ys, overlaid by Ls
  __shared__ float norms[2 * TS];                      // A-row norms | B-row norms
  float* Xs = smem;                   // [TS][XST]  A rows (= DP columns j)
  float* Ys = smem + TS * XST;        // [TS][XST]  B rows (= DP rows i)
  unsigned* Ls = (unsigned*)smem;     // [191][LST] parallelogram re-stage

  const int bz = blockIdx.z;
  const int u0 = blockIdx.y * TS;     // j tile base
  const int v0 = blockIdx.x * TS;     // i tile base
  const int bx = blockIdx.x;          // wave index of this t-range (T0 = 64*bx)
  const int tid = threadIdx.x;
  const int T0 = v0 >> 1;

  const float4* A4 = (const float4*)(A  + ((size_t)bz * NN + u0) * DD);
  const float4* B4 = (const float4*)(Bm + ((size_t)bz * NN + v0) * DD);
  #pragma unroll
  for (int q = 0; q < 8; ++q) {
    int idx = tid + 256 * q;          // 0..2047
    int r = idx >> 4, c4 = idx & 15;
    *(float4*)&Xs[r * XST + 4 * c4] = A4[idx];
    *(float4*)&Ys[r * XST + 4 * c4] = B4[idx];
  }
  __syncthreads();

  {
    const float* row = (tid < TS) ? &Xs[tid * XST] : &Ys[(tid - TS) * XST];
    float s = 0.f;
    #pragma unroll
    for (int k4 = 0; k4 < 16; ++k4) {
      float4 v = *(const float4*)&row[4 * k4];
      s += v.x * v.x + v.y * v.y + v.z * v.z + v.w * v.w;
    }
    norms[tid] = s;
  }

  const int iB = (tid >> 4) * 8;      // j-offset block
  const int jB = (tid & 15) * 8;      // i-offset block
  float acc[8][8];
  #pragma unroll
  for (int a = 0; a < 8; ++a)
    #pragma unroll
    for (int c = 0; c < 8; ++c) acc[a][c] = 0.f;

  #pragma unroll
  for (int kc = 0; kc < 16; ++kc) {
    float4 xv[8], yv[8];
    #pragma unroll
    for (int a = 0; a < 8; ++a) xv[a] = *(const float4*)&Xs[(iB + a) * XST + 4 * kc];
    #pragma unroll
    for (int c = 0; c < 8; ++c) yv[c] = *(const float4*)&Ys[(jB + c) * XST + 4 * kc];
    #pragma unroll
    for (int a = 0; a < 8; ++a)
      #pragma unroll
      for (int c = 0; c < 8; ++c) {
        float4 xa = xv[a], yc = yv[c];
        acc[a][c] = fmaf(xa.x, yc.x,
                    fmaf(xa.y, yc.y,
                    fmaf(xa.z, yc.z,
                    fmaf(xa.w, yc.w, acc[a][c]))));
      }
  }
  __syncthreads();   // Xs/Ys dead; norms visible; Ls may overwrite

  // scatter into Ls: t_local tl = (jB + cc)>>1 = tl0 + p; s_local = (iB+a) + tl
  const int tl0 = (tid & 15) * 4;
  #pragma unroll
  for (int a = 0; a < 8; ++a) {
    float uu = norms[iB + a];
    float f[8];
    #pragma unroll
    for (int cc = 0; cc < 8; ++cc)
      f[cc] = fmaf(-2.f, acc[a][cc], uu + norms[TS + jB + cc]) * INV_LN2;
    #pragma unroll
    for (int p = 0; p < 4; ++p) {
      __half2 h = __floats2half2_rn(f[2 * p], f[2 * p + 1]);   // (even i, odd i)
      int tl = tl0 + p;
      int sl = iB + a + tl;                    // s_local in [0, 191)
      Ls[sl * LST + tl] = *(unsigned*)&h;
    }
  }
  __syncthreads();

  // coalesced write-out: row r covers global s = s_base + r; valid iff (r - tl) in [0,128)
  const int tl = tid & 63;
  const int s_base = u0 + W0 * bx;
  unsigned* Sb = S + (size_t)bz * SROWS * 256 + T0 + tl;
  for (int r0 = 0; r0 < 191; r0 += 4) {
    int r = r0 + (tid >> 6);
    int jr = r - tl;
    if (r < 191 && (unsigned)jr < 128u)
      Sb[(size_t)(s_base + r) * 256] = Ls[r * LST + tl];
  }
}

// ======================= Phase 2: r8 DP_STEP, 2 batches per workgroup, raw barrier =======================
__device__ __forceinline__ float softmin_fast(float a, float b, float c)
{
  float m  = fminf(fminf(a, b), c);
  float md = __builtin_amdgcn_fmed3f(a, b, c);
  float M  = fmaxf(fmaxf(a, b), c);
  float d1 = fmaxf(m - md, -126.0f);
  float d2 = fmaxf(m - M,  -126.0f);
  float t1 = fmaf(d1, 8388608.0f, 1064992367.0f);   // (127-0.043)*2^23
  float t2 = fmaf(d2, 8388608.0f, 1064992367.0f);
  float e1 = __int_as_float((int)t1);
  float e2 = __int_as_float((int)t2);
  float s = 1.0f + e1 + e2;
  float lg = fmaf((float)__float_as_int(s), 1.19209290e-7f, -126.957f);
  return m - lg;
}

__global__ __launch_bounds__(512, 1)
void dp_kernel(const __half2* __restrict__ S, float* __restrict__ loss)
{
  __shared__ float ring2b[2][128];   // per-batch-half ring; row 0 of each stays BIG

  const int tid = threadIdx.x;
  const int half = tid >> 8;          // 0: waves 0-3 -> batch 2*bid; 1: waves 4-7 -> batch 2*bid+1
  const int t = tid & 255;            // thread-in-batch
  const int l = t & 63, w = t >> 6;   // wave-in-batch
  const int off = l + W0 * w;
  const int b = 2 * blockIdx.x + half;

  if (tid < 256) ((float*)ring2b)[tid] = BIGF;
  __syncthreads();

  float* ring = ring2b[half];

  const bool is_u0 = ((l & 15) == 0) && (l != 0);   // lanes 16,32,48: row_bcast15 path
  const bool is_l0 = (l == 0);                      // wave boundary: ring path
  const bool isw   = (l == 63) && (w < 3);          // ring writer

  const __half2* Sb = S + (size_t)b * SROWS * 256 + t;

  float aL0 = BIGF, aL1 = BIGF, hprev = BIGF;
  float nbprev = (t == 0) ? 0.f : BIGF;   // corner R[-1][-1] = 0 folded into init
  int c = -off;

  __half2 pf[16];
  #pragma unroll
  for (int q = 0; q < 16; ++q) pf[q] = Sb[(size_t)q * 256];

#define DP_STEP(SIDX)                                                          \
  {                                                                            \
    float2 del = __half22float2(pf[(SIDX) & 15]);                              \
    int shr = __builtin_amdgcn_update_dpp(__float_as_int(hprev),               \
               __float_as_int(hprev), 0x111, 0xF, 0xF, false);                 \
    int bc  = __builtin_amdgcn_update_dpp(__float_as_int(hprev),               \
               __float_as_int(hprev), 0x142, 0xF, 0xF, false);                 \
    float nbU = __int_as_float(shr);                                           \
    nbU = is_u0 ? __int_as_float(bc) : nbU;                                    \
    nbU = is_l0 ? srq : nbU;                                                   \
    float lo = del.x + softmin_fast(nbprev, nbU, aL0);                         \
    float hi = del.y + softmin_fast(aL0, lo, aL1);                             \
    bool valid = ((unsigned)c < 512u);                                         \
    lo = valid ? lo : BIGF;                                                    \
    hi = valid ? hi : BIGF;                                                    \
    nbprev = nbU; aL0 = lo; aL1 = hi; hprev = hi;                              \
    if (isw) ring[(w + 1) * 32 + (c & 31)] = hi;                               \
    pf[(SIDX) & 15] = Sb[(size_t)((SIDX) + 16) * 256];                         \
    ++c;                                                                       \
  }

  for (int sb = 0; sb < TOTM; sb += 16) {
    // batched boundary values for this block (written >= 2 steps before the barrier)
    int c0 = sb - W0 * w;
    float ringv = ring[w * 32 + ((c0 + (l & 15)) & 31)];
    #pragma unroll
    for (int q = 0; q < 16; ++q) {
      float srq = __int_as_float(
          __builtin_amdgcn_readlane(__float_as_int(ringv), q));
      DP_STEP(sb + q)
    }
    // raw barrier: drain LDS only; global prefetches stay in flight (no vmcnt drain)
    asm volatile("s_waitcnt lgkmcnt(0)\n\ts_barrier" ::: "memory");
  }
  { // epilogue: steps 800..814 (lane 255 of each half finishes at c=511 exactly)
    int c0 = TOTM - W0 * w;
    float ringv = ring[w * 32 + ((c0 + (l & 15)) & 31)];
    #pragma unroll
    for (int q = 0; q < EPI; ++q) {
      float srq = __int_as_float(
          __builtin_amdgcn_readlane(__float_as_int(ringv), q));
      DP_STEP(TOTM + q)
    }
  }

  if (t == 255)
    loss[b] = aL1 * LN2;   // R[511][511] of this half's batch
}

// ======================= Fallback (round-1 kernel, tiny ws) =======================
#define DQ 16
#define YST 68

__device__ __forceinline__ void fb_step(
    const int d, const int t, const float4* __restrict__ xr, const float xx,
    const float* __restrict__ ylds,
    const float* __restrict__ a1, const float* __restrict__ a2,
    float* __restrict__ aw, float& myP1)
{
  const int j = d - t;
  const bool valid = (j >= 0) && (j < NN);
  float dd = 0.f;
  if (valid) {
    const float* yrow = &ylds[j * YST];
    float ax = 0.f, ay = 0.f, az = 0.f, aww = 0.f;
    #pragma unroll
    for (int k = 0; k < DQ; ++k) {
      float4 v = *(const float4*)(yrow + 4 * k);
      ax  = fmaf(xr[k].x, v.x, ax);
      ay  = fmaf(xr[k].y, v.y, ay);
      az  = fmaf(xr[k].z, v.z, az);
      aww = fmaf(xr[k].w, v.w, aww);
    }
    float dot = (ax + ay) + (az + aww);
    dd = fmaf(-2.f, dot, xx + yrow[DD]);
  }
  float p1m1 = a1[t];
  float p2m1 = a2[t];
  if (t == 0) p2m1 = (d == 0) ? 0.f : BIGF;
  float m = fminf(fminf(p2m1, p1m1), myP1);
  float s = __expf(m - p2m1) + __expf(m - p1m1) + __expf(m - myP1);
  float sm = m - __logf(s);
  float cur = valid ? (dd + sm) : BIGF;
  aw[t + 1] = cur;
  myP1 = cur;
  __syncthreads();
}

__global__ __launch_bounds__(512, 2)
void dtw_fallback_kernel(const float* __restrict__ X, const float* __restrict__ Y,
                         float* __restrict__ loss)
{
  __shared__ float ylds[NN * YST];
  __shared__ float diag[3][NN + 1];

  const int b = blockIdx.x;
  const int t = threadIdx.x;

  const float4* Y4 = (const float4*)(Y + (size_t)b * NN * DD);
  for (int idx = t; idx < NN * DQ; idx += NN) {
    float4 v = Y4[idx];
    *(float4*)&ylds[(idx >> 4) * YST + (idx & 15) * 4] = v;
  }
  diag[0][t + 1] = BIGF; diag[1][t + 1] = BIGF; diag[2][t + 1] = BIGF;
  if (t == 0) { diag[0][0] = BIGF; diag[1][0] = BIGF; diag[2][0] = BIGF; }
  __syncthreads();

  float4 xr[DQ];
  float xx = 0.f;
  const float4* X4 = (const float4*)(X + (size_t)b * NN * DD + (size_t)t * DD);
  #pragma unroll
  for (int k = 0; k < DQ; ++k) {
    float4 v = X4[k];
    xr[k] = v;
    xx += v.x * v.x + v.y * v.y + v.z * v.z + v.w * v.w;
  }
  {
    float s = 0.f;
    const float* yrow = &ylds[t * YST];
    #pragma unroll
    for (int k = 0; k < DQ; ++k) {
      float4 v = *(const float4*)(yrow + 4 * k);
      s += v.x * v.x + v.y * v.y + v.z * v.z + v.w * v.w;
    }
    ylds[t * YST + DD] = s;
  }
  __syncthreads();

  float myP1 = BIGF;
  for (int dbase = 0; dbase < 2 * NN - 1; dbase += 3) {
    fb_step(dbase,     t, xr, xx, ylds, diag[2], diag[1], diag[0], myP1);
    fb_step(dbase + 1, t, xr, xx, ylds, diag[0], diag[2], diag[1], myP1);
    fb_step(dbase + 2, t, xr, xx, ylds, diag[1], diag[0], diag[2], myP1);
  }
  if (t == NN - 1) loss[b] = myP1;
}

// ======================= mean =======================
__global__ void mean_kernel(const float* __restrict__ loss, float* __restrict__ out, int B)
{
  const int t = threadIdx.x;
  float v = (t < B) ? loss[t] : 0.f;
  #pragma unroll
  for (int off = 32; off; off >>= 1) v += __shfl_down(v, off);
  if (t == 0) out[0] = v / (float)B;
}

extern "C" void kernel_launch(void* const* d_in, const int* in_sizes, int n_in,
                              void* d_out, int out_size, void* d_ws, size_t ws_size,
                              hipStream_t stream)
{
  const float* X = (const float*)d_in[0];   // input  (x, DP rows i)
  const float* Y = (const float*)d_in[1];   // target (y, DP cols j)
  float* out = (float*)d_out;
  float* ws  = (float*)d_ws;

  const int B = in_sizes[0] / (NN * DD);    // 64

  const size_t S_bytes = (size_t)B * SROWS * 256 * 4;
  const size_t need = S_bytes + 256;

  if (ws_size >= need && (B & 1) == 0) {
    float*    loss = ws;                    // B floats
    unsigned* S    = (unsigned*)(ws + 64);  // 256B offset, [b][SROWS][256] half2
    // A = Y (j rows), B = X (i rows)
    delta_kernel<<<dim3(NN / TS, NN / TS, B), 256, 0, stream>>>(Y, X, S);
    dp_kernel<<<B / 2, 512, 0, stream>>>((const __half2*)S, loss);
    mean_kernel<<<1, 64, 0, stream>>>(loss, out, B);
  } else {
    dtw_fallback_kernel<<<B, NN, 0, stream>>>(X, Y, ws);
    mean_kernel<<<1, 64, 0, stream>>>(ws, out, B);
  }
}

// Round 12
// 180.722 us; speedup vs baseline: 1.0777x; 1.0777x over previous
//
#include <hip/hip_runtime.h>
#include <hip/hip_fp16.h>

#define NN 512          // N == M
#define DD 64           // feature dim
#define BIGF 1e10f
#define INV_LN2 1.44269504088896340736f
#define LN2 0.69314718055994530942f

// DP schedule: per batch 128 threads = 2 waves; thread t owns rows 4t..4t+3.
// l = t&63, w = t>>6, off(t) = l + 80*w. At step s, lane t processes column
// c = s - off(t). S[s][t] = 4 halves ( delta[4t+r][c]/ln2, r=0..3 ), 8 B.
#define W0 80
#define NBLK 41         // 41 * 16 = 656 steps (last needed: 654)
#define SROWS 672       // >= 656 + 8 prefetch + margin

// ======================= Phase 1: delta -> schedule-order S =======================
#define TS 128
#define XST 68          // LDS stage row stride (floats)
#define LST 66          // Ls row stride (dwords)

__global__ __launch_bounds__(256, 2)
void delta_kernel(const float* __restrict__ A, const float* __restrict__ Bm,
                  unsigned* __restrict__ Sg)  // S dwords: [b][SROWS][128 slots * 2]
{
  __shared__ __align__(16) float smem[2 * TS * XST];   // Xs|Ys, overlaid by Ls
  __shared__ float norms[2 * TS];                      // A-row norms | B-row norms
  float* Xs = smem;                   // [TS][XST]  A rows (= DP columns j)
  float* Ys = smem + TS * XST;        // [TS][XST]  B rows (= DP rows i)
  unsigned* Ls = (unsigned*)smem;     // [159][LST] parallelogram re-stage

  const int bz = blockIdx.z;
  const int u0 = blockIdx.y * TS;     // j tile base
  const int v0 = blockIdx.x * TS;     // i tile base
  const int bx = blockIdx.x;          // i-tile index (t4 range [32bx, 32bx+32))
  const int tid = threadIdx.x;

  const float4* A4 = (const float4*)(A  + ((size_t)bz * NN + u0) * DD);
  const float4* B4 = (const float4*)(Bm + ((size_t)bz * NN + v0) * DD);
  #pragma unroll
  for (int q = 0; q < 8; ++q) {
    int idx = tid + 256 * q;          // 0..2047
    int r = idx >> 4, c4 = idx & 15;
    *(float4*)&Xs[r * XST + 4 * c4] = A4[idx];
    *(float4*)&Ys[r * XST + 4 * c4] = B4[idx];
  }
  __syncthreads();

  {
    const float* row = (tid < TS) ? &Xs[tid * XST] : &Ys[(tid - TS) * XST];
    float s = 0.f;
    #pragma unroll
    for (int k4 = 0; k4 < 16; ++k4) {
      float4 v = *(const float4*)&row[4 * k4];
      s += v.x * v.x + v.y * v.y + v.z * v.z + v.w * v.w;
    }
    norms[tid] = s;
  }

  const int iB = (tid >> 4) * 8;      // j-offset block
  const int jB = (tid & 15) * 8;      // i-offset block
  float acc[8][8];
  #pragma unroll
  for (int a = 0; a < 8; ++a)
    #pragma unroll
    for (int c = 0; c < 8; ++c) acc[a][c] = 0.f;

  #pragma unroll
  for (int kc = 0; kc < 16; ++kc) {
    float4 xv[8], yv[8];
    #pragma unroll
    for (int a = 0; a < 8; ++a) xv[a] = *(const float4*)&Xs[(iB + a) * XST + 4 * kc];
    #pragma unroll
    for (int c = 0; c < 8; ++c) yv[c] = *(const float4*)&Ys[(jB + c) * XST + 4 * kc];
    #pragma unroll
    for (int a = 0; a < 8; ++a)
      #pragma unroll
      for (int c = 0; c < 8; ++c) {
        float4 xa = xv[a], yc = yv[c];
        acc[a][c] = fmaf(xa.x, yc.x,
                    fmaf(xa.y, yc.y,
                    fmaf(xa.z, yc.z,
                    fmaf(xa.w, yc.w, acc[a][c]))));
      }
  }
  __syncthreads();   // Xs/Ys dead; norms visible; Ls may overwrite

  // scatter: slot g = i_local>>2, s_local = j_local + g, dword col = 2g + d
  // per a: two uint2 writes (i_local groups [jB,jB+4) and [jB+4,jB+8))
  const int g0   = 2 * (tid & 15);
  const int col0 = 4 * (tid & 15);
  #pragma unroll
  for (int a = 0; a < 8; ++a) {
    float uu = norms[iB + a];
    float f[8];
    #pragma unroll
    for (int cc = 0; cc < 8; ++cc)
      f[cc] = fmaf(-2.f, acc[a][cc], uu + norms[TS + jB + cc]) * INV_LN2;
    __half2 h01 = __floats2half2_rn(f[0], f[1]);
    __half2 h23 = __floats2half2_rn(f[2], f[3]);
    __half2 h45 = __floats2half2_rn(f[4], f[5]);
    __half2 h67 = __floats2half2_rn(f[6], f[7]);
    int sl0 = iB + a + g0;
    uint2 w0v; w0v.x = *(unsigned*)&h01; w0v.y = *(unsigned*)&h23;
    uint2 w1v; w1v.x = *(unsigned*)&h45; w1v.y = *(unsigned*)&h67;
    *(uint2*)&Ls[sl0 * LST + col0]           = w0v;
    *(uint2*)&Ls[(sl0 + 1) * LST + col0 + 2] = w1v;
  }
  __syncthreads();

  // write-out: row r -> global s = s_base + r; dword k within the tile's 64.
  // valid iff j_local = r - (k>>1) in [0,128)
  const int k = tid & 63;
  const int s_base = u0 + 32 * (bx & 1) + W0 * (bx >> 1);
  unsigned* So = Sg + (size_t)bz * SROWS * 256 + 64 * bx + k;
  for (int r0 = 0; r0 < 159; r0 += 4) {
    int r = r0 + (tid >> 6);
    if (r < 159 && (unsigned)(r - (k >> 1)) < 128u)
      So[(size_t)(s_base + r) * 256] = Ls[r * LST + k];
  }
}

// ======================= Phase 2: 4-rows-per-lane DP, named-reg prefetch =======================
__device__ __forceinline__ float softmin_fast(float a, float b, float c)
{
  float m  = fminf(fminf(a, b), c);
  float md = __builtin_amdgcn_fmed3f(a, b, c);
  float M  = fmaxf(fmaxf(a, b), c);
  float d1 = fmaxf(m - md, -126.0f);
  float d2 = fmaxf(m - M,  -126.0f);
  float t1 = fmaf(d1, 8388608.0f, 1064992367.0f);   // (127-0.043)*2^23
  float t2 = fmaf(d2, 8388608.0f, 1064992367.0f);
  float e1 = __int_as_float((int)t1);
  float e2 = __int_as_float((int)t2);
  float s = 1.0f + e1 + e2;
  float lg = fmaf((float)__float_as_int(s), 1.19209290e-7f, -126.957f);
  return m - lg;
}

__device__ __forceinline__ float dpp_shr1(float v)
{
  return __int_as_float(__builtin_amdgcn_update_dpp(
      __float_as_int(v), __float_as_int(v), 0x111, 0xF, 0xF, false));
}
__device__ __forceinline__ float dpp_bc15(float v)
{
  return __int_as_float(__builtin_amdgcn_update_dpp(
      __float_as_int(v), __float_as_int(v), 0x142, 0xF, 0xF, false));
}

__global__ __launch_bounds__(128, 1)
void dp_kernel(const uint2* __restrict__ S, float* __restrict__ loss)
{
  __shared__ float ring[2][64];   // row 0 stays BIG; row 1: w0 l63 -> w1 l0

  const int b = blockIdx.x;
  const int t = threadIdx.x;
  const int l = t & 63, w = t >> 6;
  const int off = l + W0 * w;

  ((float*)ring)[t] = BIGF;       // 128 floats, all threads
  __syncthreads();

  const bool is_u0 = ((l & 15) == 0) && (l != 0);   // lanes 16,32,48: bcast15 path
  const bool is_l0 = (l == 0);                      // wave boundary: ring path
  const bool isw   = (w == 0) && (l == 63);         // ring writer

  const uint2* Sb = S + (size_t)b * SROWS * 128 + t;

  float a0 = BIGF, a1 = BIGF, a2 = BIGF, a3 = BIGF;
  float nbprev = (t == 0) ? 0.f : BIGF;   // corner R[-1][-1]=0 folded into init
  float ans = BIGF;
  int c = -off;

  uint2 p0 = Sb[0 * 128], p1 = Sb[1 * 128], p2 = Sb[2 * 128], p3 = Sb[3 * 128];
  uint2 p4 = Sb[4 * 128], p5 = Sb[5 * 128], p6 = Sb[6 * 128], p7 = Sb[7 * 128];

#define DP_STEP4(Q, PF)                                                        \
  {                                                                            \
    float srq = __int_as_float(                                                \
        __builtin_amdgcn_readlane(__float_as_int(ringv), (Q)));                \
    float sh = dpp_shr1(a3);                                                   \
    float bc = dpp_bc15(a3);                                                   \
    float nbU = is_u0 ? bc : sh;                                               \
    nbU = is_l0 ? srq : nbU;                                                   \
    float2 dl = __half22float2(*(const __half2*)&PF.x);                        \
    float2 dh = __half22float2(*(const __half2*)&PF.y);                        \
    float r0 = dl.x + softmin_fast(nbprev, nbU, a0);                           \
    float r1 = dl.y + softmin_fast(a0, r0, a1);                                \
    float r2 = dh.x + softmin_fast(a1, r1, a2);                                \
    float r3 = dh.y + softmin_fast(a2, r2, a3);                                \
    bool valid = ((unsigned)c < 512u);                                         \
    r0 = valid ? r0 : BIGF;                                                    \
    r1 = valid ? r1 : BIGF;                                                    \
    r2 = valid ? r2 : BIGF;                                                    \
    r3 = valid ? r3 : BIGF;                                                    \
    ans = (c == 511) ? r3 : ans;                                               \
    if (isw) ring[1][c & 63] = r3;                                             \
    nbprev = nbU; a0 = r0; a1 = r1; a2 = r2; a3 = r3;                          \
    PF = Sb[(size_t)(sidx0 + (Q) + 8) * 128];                                  \
    ++c;                                                                       \
  }

  for (int blk = 0; blk < NBLK; ++blk) {
    const int sidx0 = 16 * blk;
    int c0 = sidx0 - W0 * w;
    float ringv = ring[w][(c0 + (l & 15)) & 63];
    DP_STEP4(0, p0)  DP_STEP4(1, p1)  DP_STEP4(2, p2)  DP_STEP4(3, p3)
    DP_STEP4(4, p4)  DP_STEP4(5, p5)  DP_STEP4(6, p6)  DP_STEP4(7, p7)
    DP_STEP4(8, p0)  DP_STEP4(9, p1)  DP_STEP4(10, p2) DP_STEP4(11, p3)
    DP_STEP4(12, p4) DP_STEP4(13, p5) DP_STEP4(14, p6) DP_STEP4(15, p7)
    // drain LDS only; global prefetches stay in flight (r11-proven barrier)
    asm volatile("s_waitcnt lgkmcnt(0)\n\ts_barrier" ::: "memory");
  }

  if (t == 127)
    loss[b] = ans * LN2;   // R[511][511] = lane127 r3 at c=511 (step 654)
}

// ======================= Fallback (round-1 kernel, tiny ws) =======================
#define DQ 16
#define YST 68

__device__ __forceinline__ void fb_step(
    const int d, const int t, const float4* __restrict__ xr, const float xx,
    const float* __restrict__ ylds,
    const float* __restrict__ a1, const float* __restrict__ a2,
    float* __restrict__ aw, float& myP1)
{
  const int j = d - t;
  const bool valid = (j >= 0) && (j < NN);
  float dd = 0.f;
  if (valid) {
    const float* yrow = &ylds[j * YST];
    float ax = 0.f, ay = 0.f, az = 0.f, aww = 0.f;
    #pragma unroll
    for (int k = 0; k < DQ; ++k) {
      float4 v = *(const float4*)(yrow + 4 * k);
      ax  = fmaf(xr[k].x, v.x, ax);
      ay  = fmaf(xr[k].y, v.y, ay);
      az  = fmaf(xr[k].z, v.z, az);
      aww = fmaf(xr[k].w, v.w, aww);
    }
    float dot = (ax + ay) + (az + aww);
    dd = fmaf(-2.f, dot, xx + yrow[DD]);
  }
  float p1m1 = a1[t];
  float p2m1 = a2[t];
  if (t == 0) p2m1 = (d == 0) ? 0.f : BIGF;
  float m = fminf(fminf(p2m1, p1m1), myP1);
  float s = __expf(m - p2m1) + __expf(m - p1m1) + __expf(m - myP1);
  float sm = m - __logf(s);
  float cur = valid ? (dd + sm) : BIGF;
  aw[t + 1] = cur;
  myP1 = cur;
  __syncthreads();
}

__global__ __launch_bounds__(512, 2)
void dtw_fallback_kernel(const float* __restrict__ X, const float* __restrict__ Y,
                         float* __restrict__ loss)
{
  __shared__ float ylds[NN * YST];
  __shared__ float diag[3][NN + 1];

  const int b = blockIdx.x;
  const int t = threadIdx.x;

  const float4* Y4 = (const float4*)(Y + (size_t)b * NN * DD);
  for (int idx = t; idx < NN * DQ; idx += NN) {
    float4 v = Y4[idx];
    *(float4*)&ylds[(idx >> 4) * YST + (idx & 15) * 4] = v;
  }
  diag[0][t + 1] = BIGF; diag[1][t + 1] = BIGF; diag[2][t + 1] = BIGF;
  if (t == 0) { diag[0][0] = BIGF; diag[1][0] = BIGF; diag[2][0] = BIGF; }
  __syncthreads();

  float4 xr[DQ];
  float xx = 0.f;
  const float4* X4 = (const float4*)(X + (size_t)b * NN * DD + (size_t)t * DD);
  #pragma unroll
  for (int k = 0; k < DQ; ++k) {
    float4 v = X4[k];
    xr[k] = v;
    xx += v.x * v.x + v.y * v.y + v.z * v.z + v.w * v.w;
  }
  {
    float s = 0.f;
    const float* yrow = &ylds[t * YST];
    #pragma unroll
    for (int k = 0; k < DQ; ++k) {
      float4 v = *(const float4*)(yrow + 4 * k);
      s += v.x * v.x + v.y * v.y + v.z * v.z + v.w * v.w;
    }
    ylds[t * YST + DD] = s;
  }
  __syncthreads();

  float myP1 = BIGF;
  for (int dbase = 0; dbase < 2 * NN - 1; dbase += 3) {
    fb_step(dbase,     t, xr, xx, ylds, diag[2], diag[1], diag[0], myP1);
    fb_step(dbase + 1, t, xr, xx, ylds, diag[0], diag[2], diag[1], myP1);
    fb_step(dbase + 2, t, xr, xx, ylds, diag[1], diag[0], diag[2], myP1);
  }
  if (t == NN - 1) loss[b] = myP1;
}

// ======================= mean =======================
__global__ void mean_kernel(const float* __restrict__ loss, float* __restrict__ out, int B)
{
  const int t = threadIdx.x;
  float v = (t < B) ? loss[t] : 0.f;
  #pragma unroll
  for (int off = 32; off; off >>= 1) v += __shfl_down(v, off);
  if (t == 0) out[0] = v / (float)B;
}

extern "C" void kernel_launch(void* const* d_in, const int* in_sizes, int n_in,
                              void* d_out, int out_size, void* d_ws, size_t ws_size,
                              hipStream_t stream)
{
  const float* X = (const float*)d_in[0];   // input  (x, DP rows i)
  const float* Y = (const float*)d_in[1];   // target (y, DP cols j)
  float* out = (float*)d_out;
  float* ws  = (float*)d_ws;

  const int B = in_sizes[0] / (NN * DD);    // 64

  const size_t S_bytes = (size_t)B * SROWS * 128 * 8;   // 8 B per (s, t4) slot
  const size_t need = S_bytes + 256;

  if (ws_size >= need) {
    float*    loss = ws;                    // B floats
    unsigned* Sg   = (unsigned*)(ws + 64);  // 256B offset
    // A = Y (j rows), B = X (i rows)
    delta_kernel<<<dim3(NN / TS, NN / TS, B), 256, 0, stream>>>(Y, X, Sg);
    dp_kernel<<<B, 128, 0, stream>>>((const uint2*)Sg, loss);
    mean_kernel<<<1, 64, 0, stream>>>(loss, out, B);
  } else {
    dtw_fallback_kernel<<<B, NN, 0, stream>>>(X, Y, ws);
    mean_kernel<<<1, 64, 0, stream>>>(ws, out, B);
  }
}

// Round 13
// 115.176 us; speedup vs baseline: 1.6910x; 1.5691x over previous
//
#include <hip/hip_runtime.h>
#include <hip/hip_fp16.h>

#define NN 512          // N == M
#define DD 64           // feature dim
#define BIGF 1e10f
#define INV_LN2 1.44269504088896340736f
#define LN2 0.69314718055994530942f

// DP schedule (r8, proven): per batch 256 threads = 4 waves; thread t owns rows
// 2t, 2t+1; l = t&63, w = t>>6; off(t) = l + 80*w. At step s lane t does column
// c = s - off(t). S[s][t] = half2( delta[2t][c], delta[2t+1][c] ) / ln2.
#define W0 80
#define TOTM 800        // 50 full 16-step blocks
#define EPI 15          // +15 epilogue steps -> last step s = 814
#define SROWS 832       // >= 814 + 16 prefetch + 1

// ======================= Phase 1: MFMA delta -> schedule-order S =======================
#define TS 128
#define HST 72          // LDS half-row stride (64 + 8 pad halves; 144 B rows)
#define LST 66          // Ls row stride (dwords)

typedef _Float16 v8h __attribute__((ext_vector_type(8)));
typedef float v4f __attribute__((ext_vector_type(4)));

__global__ __launch_bounds__(256, 2)
void delta_kernel(const float* __restrict__ A, const float* __restrict__ Bm,
                  unsigned* __restrict__ Sg)   // S dwords [b][SROWS][256]
{
  __shared__ __align__(16) char smem[191 * LST * 4];   // 50424 B: Ah|Bh, then Ls
  __shared__ float norms[2 * TS];                      // A-row (yy) | B-row (xx)
  _Float16* Ah = (_Float16*)smem;            // [TS][HST]  A rows (= DP columns j)
  _Float16* Bh = Ah + TS * HST;              // [TS][HST]  B rows (= DP rows i)
  unsigned* Ls = (unsigned*)smem;            // [191][LST] parallelogram re-stage
  _Float16* Lh = (_Float16*)smem;            // half view of Ls

  const int bz = blockIdx.z;
  const int u0 = blockIdx.y * TS;     // j tile base
  const int v0 = blockIdx.x * TS;     // i tile base
  const int bx = blockIdx.x;
  const int tid = threadIdx.x;
  const int T0 = v0 >> 1;

  // ---- stage + f32->f16 convert ----
  const float4* A4 = (const float4*)(A  + ((size_t)bz * NN + u0) * DD);
  const float4* B4 = (const float4*)(Bm + ((size_t)bz * NN + v0) * DD);
  #pragma unroll
  for (int q = 0; q < 8; ++q) {
    int idx = tid + 256 * q;          // 0..2047
    int r = idx >> 4, c4 = idx & 15;
    float4 va = A4[idx], vb = B4[idx];
    __half2 a01 = __floats2half2_rn(va.x, va.y);
    __half2 a23 = __floats2half2_rn(va.z, va.w);
    __half2 b01 = __floats2half2_rn(vb.x, vb.y);
    __half2 b23 = __floats2half2_rn(vb.z, vb.w);
    uint2 ua; ua.x = *(unsigned*)&a01; ua.y = *(unsigned*)&a23;
    uint2 ub; ub.x = *(unsigned*)&b01; ub.y = *(unsigned*)&b23;
    *(uint2*)&Ah[r * HST + 4 * c4] = ua;
    *(uint2*)&Bh[r * HST + 4 * c4] = ub;
  }
  __syncthreads();

  // ---- row norms from f16 values (consistent with MFMA dot) ----
  {
    const _Float16* row = (tid < TS) ? &Ah[tid * HST] : &Bh[(tid - TS) * HST];
    float s = 0.f;
    #pragma unroll
    for (int q = 0; q < 8; ++q) {
      v8h v = *(const v8h*)&row[8 * q];
      #pragma unroll
      for (int e = 0; e < 8; ++e) { float x = (float)v[e]; s = fmaf(x, x, s); }
    }
    norms[tid] = s;
  }

  // ---- MFMA: wave w covers j-strip [32w,32w+32) x all 128 i ----
  const int l = tid & 63, w = tid >> 6;
  const int la = l & 15, lb = l >> 4;

  v4f acc[2][8];
  #pragma unroll
  for (int jf = 0; jf < 2; ++jf)
    #pragma unroll
    for (int f = 0; f < 8; ++f) acc[jf][f] = (v4f){0.f, 0.f, 0.f, 0.f};

  #pragma unroll
  for (int kf = 0; kf < 2; ++kf) {
    v8h af0 = *(const v8h*)&Ah[(32 * w + la) * HST + 32 * kf + 8 * lb];
    v8h af1 = *(const v8h*)&Ah[(32 * w + 16 + la) * HST + 32 * kf + 8 * lb];
    #pragma unroll
    for (int f = 0; f < 8; ++f) {
      v8h bf = *(const v8h*)&Bh[(16 * f + la) * HST + 32 * kf + 8 * lb];
      acc[0][f] = __builtin_amdgcn_mfma_f32_16x16x32_f16(af0, bf, acc[0][f], 0, 0, 0);
      acc[1][f] = __builtin_amdgcn_mfma_f32_16x16x32_f16(af1, bf, acc[1][f], 0, 0, 0);
    }
  }
  __syncthreads();   // Ah/Bh dead; norms visible; Ls may overwrite

  // ---- epilogue: delta -> half -> Ls parallelogram (r8 layout) ----
  // D layout: col (i) = la, row (j) = 4*lb + reg
  #pragma unroll
  for (int jf = 0; jf < 2; ++jf) {
    #pragma unroll
    for (int r = 0; r < 4; ++r) {
      int jl = 32 * w + 16 * jf + 4 * lb + r;
      float yy = norms[jl];
      #pragma unroll
      for (int f = 0; f < 8; ++f) {
        int il = 16 * f + la;
        float xx = norms[TS + il];
        float d = fmaf(-2.f, acc[jf][f][r], xx + yy) * INV_LN2;
        int tl = il >> 1;
        int sl = jl + tl;                       // s_local in [0,191)
        Lh[(sl * LST + tl) * 2 + (il & 1)] = (_Float16)d;
      }
    }
  }
  __syncthreads();

  // ---- coalesced write-out (r8 verbatim): row rr -> global s = s_base + rr ----
  const int k = tid & 63;
  const int s_base = u0 + W0 * bx;
  unsigned* So = Sg + (size_t)bz * SROWS * 256 + T0 + k;
  for (int r0 = 0; r0 < 191; r0 += 4) {
    int rr = r0 + (tid >> 6);
    if (rr < 191 && (unsigned)(rr - k) < 128u)
      So[(size_t)(s_base + rr) * 256] = Ls[rr * LST + k];
  }
}

// ======================= Phase 2: r8 dp_kernel (verbatim, proven 93 us) =======================
__device__ __forceinline__ float softmin_fast(float a, float b, float c)
{
  float m  = fminf(fminf(a, b), c);
  float md = __builtin_amdgcn_fmed3f(a, b, c);
  float M  = fmaxf(fmaxf(a, b), c);
  float d1 = fmaxf(m - md, -126.0f);
  float d2 = fmaxf(m - M,  -126.0f);
  float t1 = fmaf(d1, 8388608.0f, 1064992367.0f);   // (127-0.043)*2^23
  float t2 = fmaf(d2, 8388608.0f, 1064992367.0f);
  float e1 = __int_as_float((int)t1);
  float e2 = __int_as_float((int)t2);
  float s = 1.0f + e1 + e2;
  float lg = fmaf((float)__float_as_int(s), 1.19209290e-7f, -126.957f);
  return m - lg;
}

__global__ __launch_bounds__(256, 1)
void dp_kernel(const __half2* __restrict__ S, float* __restrict__ loss)
{
  __shared__ float ring[4 * 32];     // per-wave boundary ring; row 0 stays BIG

  const int b = blockIdx.x;
  const int t = threadIdx.x;
  const int l = t & 63, w = t >> 6;
  const int off = l + W0 * w;

  if (t < 128) ring[t] = BIGF;
  __syncthreads();

  const bool is_u0 = ((l & 15) == 0) && (l != 0);   // lanes 16,32,48: row_bcast15 path
  const bool is_l0 = (l == 0);                      // wave boundary: SGPR ring path
  const bool isw   = (l == 63) && (w < 3);          // ring writer

  const __half2* Sb = S + (size_t)b * SROWS * 256 + t;

  float aL0 = BIGF, aL1 = BIGF, hprev = BIGF;
  float nbprev = (t == 0) ? 0.f : BIGF;   // corner R[-1][-1] = 0 folded into init
  int c = -off;

  __half2 pf[16];
  #pragma unroll
  for (int q = 0; q < 16; ++q) pf[q] = Sb[(size_t)q * 256];

#define DP_STEP(SIDX)                                                          \
  {                                                                            \
    float2 del = __half22float2(pf[(SIDX) & 15]);                              \
    int shr = __builtin_amdgcn_update_dpp(__float_as_int(hprev),               \
               __float_as_int(hprev), 0x111, 0xF, 0xF, false);                 \
    int bc  = __builtin_amdgcn_update_dpp(__float_as_int(hprev),               \
               __float_as_int(hprev), 0x142, 0xF, 0xF, false);                 \
    float nbU = __int_as_float(shr);                                           \
    nbU = is_u0 ? __int_as_float(bc) : nbU;                                    \
    nbU = is_l0 ? srq : nbU;                                                   \
    float lo = del.x + softmin_fast(nbprev, nbU, aL0);                         \
    float hi = del.y + softmin_fast(aL0, lo, aL1);                             \
    bool valid = ((unsigned)c < 512u);                                         \
    lo = valid ? lo : BIGF;                                                    \
    hi = valid ? hi : BIGF;                                                    \
    nbprev = nbU; aL0 = lo; aL1 = hi; hprev = hi;                              \
    if (isw) ring[(w + 1) * 32 + (c & 31)] = hi;                               \
    pf[(SIDX) & 15] = Sb[(size_t)((SIDX) + 16) * 256];                         \
    ++c;                                                                       \
  }

  for (int sb = 0; sb < TOTM; sb += 16) {
    int c0 = sb - W0 * w;
    float ringv = ring[w * 32 + ((c0 + (l & 15)) & 31)];
    #pragma unroll
    for (int q = 0; q < 16; ++q) {
      float srq = __int_as_float(
          __builtin_amdgcn_readlane(__float_as_int(ringv), q));
      DP_STEP(sb + q)
    }
    __syncthreads();
  }
  { // epilogue: steps 800..814 (lane 255 finishes at c=511 exactly)
    int c0 = TOTM - W0 * w;
    float ringv = ring[w * 32 + ((c0 + (l & 15)) & 31)];
    #pragma unroll
    for (int q = 0; q < EPI; ++q) {
      float srq = __int_as_float(
          __builtin_amdgcn_readlane(__float_as_int(ringv), q));
      DP_STEP(TOTM + q)
    }
  }

  if (t == 255)
    loss[b] = aL1 * LN2;   // R[511][511]
}

// ======================= Fallback (round-1 kernel, tiny ws) =======================
#define DQ 16
#define YST 68

__device__ __forceinline__ void fb_step(
    const int d, const int t, const float4* __restrict__ xr, const float xx,
    const float* __restrict__ ylds,
    const float* __restrict__ a1, const float* __restrict__ a2,
    float* __restrict__ aw, float& myP1)
{
  const int j = d - t;
  const bool valid = (j >= 0) && (j < NN);
  float dd = 0.f;
  if (valid) {
    const float* yrow = &ylds[j * YST];
    float ax = 0.f, ay = 0.f, az = 0.f, aww = 0.f;
    #pragma unroll
    for (int k = 0; k < DQ; ++k) {
      float4 v = *(const float4*)(yrow + 4 * k);
      ax  = fmaf(xr[k].x, v.x, ax);
      ay  = fmaf(xr[k].y, v.y, ay);
      az  = fmaf(xr[k].z, v.z, az);
      aww = fmaf(xr[k].w, v.w, aww);
    }
    float dot = (ax + ay) + (az + aww);
    dd = fmaf(-2.f, dot, xx + yrow[DD]);
  }
  float p1m1 = a1[t];
  float p2m1 = a2[t];
  if (t == 0) p2m1 = (d == 0) ? 0.f : BIGF;
  float m = fminf(fminf(p2m1, p1m1), myP1);
  float s = __expf(m - p2m1) + __expf(m - p1m1) + __expf(m - myP1);
  float sm = m - __logf(s);
  float cur = valid ? (dd + sm) : BIGF;
  aw[t + 1] = cur;
  myP1 = cur;
  __syncthreads();
}

__global__ __launch_bounds__(512, 2)
void dtw_fallback_kernel(const float* __restrict__ X, const float* __restrict__ Y,
                         float* __restrict__ loss)
{
  __shared__ float ylds[NN * YST];
  __shared__ float diag[3][NN + 1];

  const int b = blockIdx.x;
  const int t = threadIdx.x;

  const float4* Y4 = (const float4*)(Y + (size_t)b * NN * DD);
  for (int idx = t; idx < NN * DQ; idx += NN) {
    float4 v = Y4[idx];
    *(float4*)&ylds[(idx >> 4) * YST + (idx & 15) * 4] = v;
  }
  diag[0][t + 1] = BIGF; diag[1][t + 1] = BIGF; diag[2][t + 1] = BIGF;
  if (t == 0) { diag[0][0] = BIGF; diag[1][0] = BIGF; diag[2][0] = BIGF; }
  __syncthreads();

  float4 xr[DQ];
  float xx = 0.f;
  const float4* X4 = (const float4*)(X + (size_t)b * NN * DD + (size_t)t * DD);
  #pragma unroll
  for (int k = 0; k < DQ; ++k) {
    float4 v = X4[k];
    xr[k] = v;
    xx += v.x * v.x + v.y * v.y + v.z * v.z + v.w * v.w;
  }
  {
    float s = 0.f;
    const float* yrow = &ylds[t * YST];
    #pragma unroll
    for (int k = 0; k < DQ; ++k) {
      float4 v = *(const float4*)(yrow + 4 * k);
      s += v.x * v.x + v.y * v.y + v.z * v.z + v.w * v.w;
    }
    ylds[t * YST + DD] = s;
  }
  __syncthreads();

  float myP1 = BIGF;
  for (int dbase = 0; dbase < 2 * NN - 1; dbase += 3) {
    fb_step(dbase,     t, xr, xx, ylds, diag[2], diag[1], diag[0], myP1);
    fb_step(dbase + 1, t, xr, xx, ylds, diag[0], diag[2], diag[1], myP1);
    fb_step(dbase + 2, t, xr, xx, ylds, diag[1], diag[0], diag[2], myP1);
  }
  if (t == NN - 1) loss[b] = myP1;
}

// ======================= mean =======================
__global__ void mean_kernel(const float* __restrict__ loss, float* __restrict__ out, int B)
{
  const int t = threadIdx.x;
  float v = (t < B) ? loss[t] : 0.f;
  #pragma unroll
  for (int off = 32; off; off >>= 1) v += __shfl_down(v, off);
  if (t == 0) out[0] = v / (float)B;
}

extern "C" void kernel_launch(void* const* d_in, const int* in_sizes, int n_in,
                              void* d_out, int out_size, void* d_ws, size_t ws_size,
                              hipStream_t stream)
{
  const float* X = (const float*)d_in[0];   // input  (x, DP rows i)
  const float* Y = (const float*)d_in[1];   // target (y, DP cols j)
  float* out = (float*)d_out;
  float* ws  = (float*)d_ws;

  const int B = in_sizes[0] / (NN * DD);    // 64

  const size_t S_bytes = (size_t)B * SROWS * 256 * 4;
  const size_t need = S_bytes + 256;

  if (ws_size >= need) {
    float*    loss = ws;                    // B floats
    unsigned* Sg   = (unsigned*)(ws + 64);  // 256B offset, [b][SROWS][256] half2
    // A = Y (j rows), B = X (i rows)
    delta_kernel<<<dim3(NN / TS, NN / TS, B), 256, 0, stream>>>(Y, X, Sg);
    dp_kernel<<<B, 256, 0, stream>>>((const __half2*)Sg, loss);
    mean_kernel<<<1, 64, 0, stream>>>(loss, out, B);
  } else {
    dtw_fallback_kernel<<<B, NN, 0, stream>>>(X, Y, ws);
    mean_kernel<<<1, 64, 0, stream>>>(ws, out, B);
  }
}